// Round 1
// baseline (103.569 us; speedup 1.0000x reference)
//
#include <hip/hip_runtime.h>

#define N 8192
#define Dk 128
#define EPSC 1e-6f
#define MARGIN 0.2f

#define BI 64
#define BJ 128
#define JSPLIT 4
#define LDA 136  // padded LDS row stride in bf16 elems (136*2=272B = 17*16B, keeps 16B align + uniform banks)

typedef __attribute__((ext_vector_type(8))) short bf16x8;
typedef __attribute__((ext_vector_type(4))) float f32x4;

__device__ __forceinline__ unsigned short f2bf(float f) {
    unsigned u = __float_as_uint(f);
    u = (u + 0x7FFFu + ((u >> 16) & 1u)) >> 16;  // RNE fp32->bf16
    return (unsigned short)u;
}
// monotone float->uint encoding so atomicMax/Min on unsigned works for signed floats
__device__ __forceinline__ unsigned enc(float f) {
    unsigned u = __float_as_uint(f);
    return (u & 0x80000000u) ? ~u : (u | 0x80000000u);
}
__device__ __forceinline__ float dec(unsigned u) {
    return __uint_as_float((u & 0x80000000u) ? (u & 0x7FFFFFFFu) : ~u);
}

// Kernel A: bf16 cast of x, per-row P/Q, stat-array init. One wave per row.
__global__ void prep_kernel(const float* __restrict__ x,
                            unsigned short* __restrict__ Xb,
                            float* __restrict__ P, float* __restrict__ Q,
                            unsigned* __restrict__ wsHp, unsigned* __restrict__ wsMn) {
    int gtid = blockIdx.x * blockDim.x + threadIdx.x;
    int row = gtid >> 6;
    int lane = gtid & 63;
    const float2 v = *reinterpret_cast<const float2*>(&x[row * Dk + lane * 2]);
    float sq = v.x * v.x + v.y * v.y;
    float s = v.x + v.y;
    ushort2 o;
    o.x = f2bf(v.x);
    o.y = f2bf(v.y);
    *reinterpret_cast<ushort2*>(&Xb[row * Dk + lane * 2]) = o;
#pragma unroll
    for (int m = 32; m >= 1; m >>= 1) {
        sq += __shfl_xor(sq, m);
        s += __shfl_xor(s, m);
    }
    if (lane == 0) {
        P[row] = sq - 2.0f * EPSC * s;
        Q[row] = sq + 2.0f * EPSC * s + (float)Dk * EPSC * EPSC;
        wsHp[row] = 0x007FFFFFu;  // enc(-inf): identity for max
        wsMn[row] = 0xFF800000u;  // enc(+inf): identity for min
    }
}

// Kernel B: tiled X*X^T via bf16 MFMA with fused masked min/max epilogue in d2-space.
// Block: 64 anchors x 2048 j-columns (16 steps of 128). 4 waves side-by-side in j.
__global__ __launch_bounds__(256) void main_kernel(
        const unsigned short* __restrict__ Xb,
        const float* __restrict__ Q,
        const int* __restrict__ tgt,
        unsigned* __restrict__ wsHp, unsigned* __restrict__ wsMn) {
    __shared__ unsigned short As[BI * LDA];
    __shared__ unsigned short Bs[BJ * LDA];
    __shared__ float Qs[BJ];
    __shared__ int Ts[BJ];

    const int tid = threadIdx.x;
    const int w = tid >> 6;      // wave 0..3
    const int lane = tid & 63;
    const int n = lane & 15;     // MFMA col / frag row index
    const int q = lane >> 4;     // quad 0..3

    const int ig = (int)blockIdx.x >> 2;  // row-group
    const int js = (int)blockIdx.x & 3;   // j-split
    const int i0 = ig * BI;
    const int jstart = js * (N / JSPLIT);

    const uint4* Xb4 = reinterpret_cast<const uint4*>(Xb);

    // Stage A tile once: 64 rows x 16 uint4 (coalesced read, uniform-bank LDS write)
#pragma unroll
    for (int it = 0; it < 4; ++it) {
        int idx = tid + 256 * it;
        int r = idx >> 4, c = idx & 15;
        uint4 v = Xb4[(i0 + r) * 16 + c];
        *reinterpret_cast<uint4*>(&As[r * LDA + c * 8]) = v;
    }

    // anchor targets for this lane's 16 row-slots: i = i0 + 16*ti + 4*q + r
    int tslot[16];
#pragma unroll
    for (int ti = 0; ti < 4; ++ti) {
        int4 t4 = *reinterpret_cast<const int4*>(&tgt[i0 + 16 * ti + 4 * q]);
        tslot[ti * 4 + 0] = t4.x;
        tslot[ti * 4 + 1] = t4.y;
        tslot[ti * 4 + 2] = t4.z;
        tslot[ti * 4 + 3] = t4.w;
    }

    // running stats in val-space (val = Q_j - 2*dot; d2 = P_i + val, P applied later)
    float hp[16], mn[16];
#pragma unroll
    for (int s = 0; s < 16; ++s) {
        hp[s] = -INFINITY;  // max over same-class
        mn[s] = INFINITY;   // min over diff-class
    }

    int aoff[4], boff[2];
#pragma unroll
    for (int ti = 0; ti < 4; ++ti) aoff[ti] = (16 * ti + n) * LDA + q * 8;
#pragma unroll
    for (int tj = 0; tj < 2; ++tj) boff[tj] = (32 * w + 16 * tj + n) * LDA + q * 8;

    for (int step = 0; step < (N / JSPLIT) / BJ; ++step) {
        const int jbase = jstart + step * BJ;
        __syncthreads();  // previous iteration's Bs/Qs/Ts reads done
        // Stage B tile: 128 rows x 16 uint4
#pragma unroll
        for (int it = 0; it < 8; ++it) {
            int idx = tid + 256 * it;
            int r = idx >> 4, c = idx & 15;
            uint4 v = Xb4[(jbase + r) * 16 + c];
            *reinterpret_cast<uint4*>(&Bs[r * LDA + c * 8]) = v;
        }
        if (tid < BJ) Qs[tid] = Q[jbase + tid];
        else Ts[tid - BJ] = tgt[jbase + tid - BJ];
        __syncthreads();

        f32x4 acc[4][2];
#pragma unroll
        for (int ti = 0; ti < 4; ++ti)
#pragma unroll
            for (int tj = 0; tj < 2; ++tj) acc[ti][tj] = 0.0f;

#pragma unroll
        for (int kk = 0; kk < 4; ++kk) {
            bf16x8 b0 = *reinterpret_cast<const bf16x8*>(&Bs[boff[0] + kk * 32]);
            bf16x8 b1 = *reinterpret_cast<const bf16x8*>(&Bs[boff[1] + kk * 32]);
#pragma unroll
            for (int ti = 0; ti < 4; ++ti) {
                bf16x8 a = *reinterpret_cast<const bf16x8*>(&As[aoff[ti] + kk * 32]);
                acc[ti][0] = __builtin_amdgcn_mfma_f32_16x16x32_bf16(a, b0, acc[ti][0], 0, 0, 0);
                acc[ti][1] = __builtin_amdgcn_mfma_f32_16x16x32_bf16(a, b1, acc[ti][1], 0, 0, 0);
            }
        }

        // epilogue: D element (lane) -> row m=(q*4+r) of tile ti, col n of tile tj
#pragma unroll
        for (int tj = 0; tj < 2; ++tj) {
            int col = 32 * w + 16 * tj + n;
            float Qv = Qs[col];
            int tv = Ts[col];
#pragma unroll
            for (int ti = 0; ti < 4; ++ti) {
#pragma unroll
                for (int r = 0; r < 4; ++r) {
                    float val = fmaf(-2.0f, acc[ti][tj][r], Qv);
                    int sidx = ti * 4 + r;
                    bool sm = (tv == tslot[sidx]);
                    hp[sidx] = sm ? fmaxf(hp[sidx], val) : hp[sidx];
                    mn[sidx] = sm ? mn[sidx] : fminf(mn[sidx], val);
                }
            }
        }
    }

    // reduce across the 16 lanes (n = lane&15) of each quad
#pragma unroll
    for (int m = 1; m <= 8; m <<= 1) {
#pragma unroll
        for (int s = 0; s < 16; ++s) {
            hp[s] = fmaxf(hp[s], __shfl_xor(hp[s], m));
            mn[s] = fminf(mn[s], __shfl_xor(mn[s], m));
        }
    }
    if (n == 0) {
#pragma unroll
        for (int ti = 0; ti < 4; ++ti) {
#pragma unroll
            for (int r = 0; r < 4; ++r) {
                int i = i0 + 16 * ti + 4 * q + r;
                atomicMax(&wsHp[i], enc(hp[ti * 4 + r]));
                atomicMin(&wsMn[i], enc(mn[ti * 4 + r]));
            }
        }
    }
}

// Kernel C: per-anchor loss + mean
__global__ void finish_kernel(const float* __restrict__ P,
                              const unsigned* __restrict__ wsHp,
                              const unsigned* __restrict__ wsMn,
                              float* __restrict__ out) {
    int i = blockIdx.x * 256 + threadIdx.x;
    float Pi = P[i];
    float hp = sqrtf(fmaxf(Pi + dec(wsHp[i]), 0.0f));
    float hn = sqrtf(fmaxf(Pi + dec(wsMn[i]), 0.0f));
    float loss = fmaxf(hp - hn + MARGIN, 0.0f) * (1.0f / (float)N);
#pragma unroll
    for (int m = 32; m >= 1; m >>= 1) loss += __shfl_xor(loss, m);
    __shared__ float wsum[4];
    int lane = threadIdx.x & 63, wv = threadIdx.x >> 6;
    if (lane == 0) wsum[wv] = loss;
    __syncthreads();
    if (threadIdx.x == 0) atomicAdd(out, wsum[0] + wsum[1] + wsum[2] + wsum[3]);
}

extern "C" void kernel_launch(void* const* d_in, const int* in_sizes, int n_in,
                              void* d_out, int out_size, void* d_ws, size_t ws_size,
                              hipStream_t stream) {
    const float* x = (const float*)d_in[0];
    const int* tgt = (const int*)d_in[1];
    float* out = (float*)d_out;

    char* ws = (char*)d_ws;
    const size_t xb_bytes = (size_t)N * Dk * 2;  // 2 MB
    unsigned short* Xb = (unsigned short*)ws;
    float* P = (float*)(ws + xb_bytes);
    float* Q = (float*)(ws + xb_bytes + (size_t)N * 4);
    unsigned* wsHp = (unsigned*)(ws + xb_bytes + (size_t)N * 8);
    unsigned* wsMn = (unsigned*)(ws + xb_bytes + (size_t)N * 12);

    hipMemsetAsync(d_out, 0, sizeof(float), stream);
    prep_kernel<<<N / 4, 256, 0, stream>>>(x, Xb, P, Q, wsHp, wsMn);
    main_kernel<<<(N / BI) * JSPLIT, 256, 0, stream>>>(Xb, Q, tgt, wsHp, wsMn);
    finish_kernel<<<N / 256, 256, 0, stream>>>(P, wsHp, wsMn, out);
}

// Round 2
// 98.325 us; speedup vs baseline: 1.0533x; 1.0533x over previous
//
#include <hip/hip_runtime.h>

#define N 8192
#define Dk 128
#define EPSC 1e-6f
#define MARGIN 0.2f

typedef __attribute__((ext_vector_type(8))) short bf16x8;
typedef __attribute__((ext_vector_type(4))) float f32x4;

__device__ __forceinline__ unsigned short f2bf(float f) {
    unsigned u = __float_as_uint(f);
    u = (u + 0x7FFFu + ((u >> 16) & 1u)) >> 16;  // RNE fp32->bf16
    return (unsigned short)u;
}
// monotone float->uint encoding so atomicMax/Min on unsigned orders like float
__device__ __forceinline__ unsigned enc(float f) {
    unsigned u = __float_as_uint(f);
    return (u & 0x80000000u) ? ~u : (u | 0x80000000u);
}
__device__ __forceinline__ float dec(unsigned u) {
    return __uint_as_float((u & 0x80000000u) ? (u & 0x7FFFFFFFu) : ~u);
}

__device__ __forceinline__ void gl_lds16(const void* src, void* lds_dst) {
    __builtin_amdgcn_global_load_lds(
        (const __attribute__((address_space(1))) unsigned*)src,
        (__attribute__((address_space(3))) unsigned*)lds_dst, 16, 0, 0);
}

// Kernel A: swizzled bf16 copies of x (XbA = x, XbB = -2x), per-row P and QT, stat init.
// One wave per row. Swizzle: 16B chunk c of row r stored at chunk (c ^ (r&7)).
__global__ void prep_kernel(const float* __restrict__ x, const int* __restrict__ tgt,
                            unsigned short* __restrict__ XbA, unsigned short* __restrict__ XbB,
                            uint2* __restrict__ QT, float* __restrict__ P,
                            unsigned* __restrict__ wsHp, unsigned* __restrict__ wsMn) {
    int row = blockIdx.x * 4 + (threadIdx.x >> 6);
    int l = threadIdx.x & 63;
    const float2 v = *reinterpret_cast<const float2*>(&x[row * Dk + l * 2]);
    float sq = fmaf(v.x, v.x, v.y * v.y);
    float s = v.x + v.y;
    ushort2 a, b;
    a.x = f2bf(v.x);
    a.y = f2bf(v.y);
    b.x = f2bf(-2.0f * v.x);
    b.y = f2bf(-2.0f * v.y);
    int c_phys = (l >> 2) ^ (row & 7);
    int off = row * Dk + c_phys * 8 + 2 * (l & 3);
    *reinterpret_cast<ushort2*>(&XbA[off]) = a;
    *reinterpret_cast<ushort2*>(&XbB[off]) = b;
#pragma unroll
    for (int m = 32; m >= 1; m >>= 1) {
        sq += __shfl_xor(sq, m);
        s += __shfl_xor(s, m);
    }
    if (l == 0) {
        P[row] = sq - 2.0f * EPSC * s;
        uint2 qt;
        qt.x = __float_as_uint(sq + 2.0f * EPSC * s + (float)Dk * EPSC * EPSC);
        qt.y = (unsigned)tgt[row];
        QT[row] = qt;
        wsHp[row] = 0x007FFFFFu;  // enc(-inf)
        wsMn[row] = 0xFF800000u;  // enc(+inf)
    }
}

// Kernel B: block = 128 anchors x 1024 j (8 steps of 128). 4 waves, each 64i x 64j.
// A fragments persistent in registers; B staged to LDS via global_load_lds;
// acc initialized to Q_j; B pre-scaled by -2 so acc = Q_j - 2*dot after MFMA.
__global__ __launch_bounds__(256, 2) void main_kernel(
        const unsigned short* __restrict__ XbA, const unsigned short* __restrict__ XbB,
        const uint2* __restrict__ QT, const int* __restrict__ tgt,
        unsigned* __restrict__ wsHp, unsigned* __restrict__ wsMn) {
    __shared__ unsigned short Bs[128 * Dk];
    __shared__ uint2 QTs[128];

    const int tid = threadIdx.x;
    const int w = tid >> 6;
    const int lane = tid & 63;
    const int n = lane & 15;
    const int q = lane >> 4;
    const int wi = w >> 1;  // wave's i-half
    const int wj = w & 1;   // wave's j-half
    const int sw = n & 7;   // swizzle key (row&7 == n&7 for all our rows)

    const int ig = (int)blockIdx.x >> 3;
    const int js = (int)blockIdx.x & 7;
    const int i0 = ig * 128;
    const int rbase = i0 + 64 * wi;

    // Persistent A fragments: 64 rows x K=128 per wave
    bf16x8 Af[4][4];
#pragma unroll
    for (int ti = 0; ti < 4; ++ti) {
        const unsigned short* rp = &XbA[(rbase + 16 * ti + n) * Dk];
#pragma unroll
        for (int kk = 0; kk < 4; ++kk)
            Af[ti][kk] = *reinterpret_cast<const bf16x8*>(&rp[((q + 4 * kk) ^ sw) << 3]);
    }

    // anchor classes for this lane's 16 row-slots: row = rbase + 16*ti + 4*q + r
    int tsl[16];
#pragma unroll
    for (int ti = 0; ti < 4; ++ti) {
        int4 t4 = *reinterpret_cast<const int4*>(&tgt[rbase + 16 * ti + 4 * q]);
        tsl[4 * ti + 0] = t4.x;
        tsl[4 * ti + 1] = t4.y;
        tsl[4 * ti + 2] = t4.z;
        tsl[4 * ti + 3] = t4.w;
    }

    float hp[16], mn[16];
#pragma unroll
    for (int s = 0; s < 16; ++s) {
        hp[s] = -INFINITY;
        mn[s] = INFINITY;
    }

    for (int step = 0; step < 8; ++step) {
        const int jbase = js * 1024 + step * 128;
        __syncthreads();  // previous step's Bs/QTs reads complete
        // Stage B tile (32 KB): wave w copies rows 32w..32w+31, 1 KB per instruction
#pragma unroll
        for (int t = 0; t < 8; ++t) {
            const unsigned short* src = &XbB[(jbase + 32 * w + 4 * t) * Dk] + lane * 8;
            unsigned short* dst = &Bs[(32 * w + 4 * t) * Dk];
            gl_lds16(src, dst);
        }
        if (w == 0) {  // QT for the 128 j's: 1 KB in one instruction
            const unsigned short* src = reinterpret_cast<const unsigned short*>(&QT[jbase]) + lane * 8;
            gl_lds16(src, &QTs[0]);
        }
        __syncthreads();

        float Qv[4];
        int tv[4];
#pragma unroll
        for (int tj = 0; tj < 4; ++tj) {
            uint2 qt = QTs[64 * wj + 16 * tj + n];
            Qv[tj] = __uint_as_float(qt.x);
            tv[tj] = (int)qt.y;
        }

        f32x4 acc[4][4];
#pragma unroll
        for (int ti = 0; ti < 4; ++ti)
#pragma unroll
            for (int tj = 0; tj < 4; ++tj) acc[ti][tj] = Qv[tj];  // splat: acc = Q_j

#pragma unroll
        for (int kk = 0; kk < 4; ++kk) {
            bf16x8 Bf[4];
#pragma unroll
            for (int tj = 0; tj < 4; ++tj)
                Bf[tj] = *reinterpret_cast<const bf16x8*>(
                    &Bs[(64 * wj + 16 * tj + n) * Dk + (((q + 4 * kk) ^ sw) << 3)]);
#pragma unroll
            for (int ti = 0; ti < 4; ++ti)
#pragma unroll
                for (int tj = 0; tj < 4; ++tj)
                    acc[ti][tj] = __builtin_amdgcn_mfma_f32_16x16x32_bf16(Af[ti][kk], Bf[tj],
                                                                          acc[ti][tj], 0, 0, 0);
        }

        // Epilogue: acc element r is (row rbase+16ti+4q+r, col jbase+64wj+16tj+n), value Q_j-2dot
#pragma unroll
        for (int tj = 0; tj < 4; ++tj) {
            int tvv = tv[tj];
#pragma unroll
            for (int ti = 0; ti < 4; ++ti) {
                f32x4 v = acc[ti][tj];
                int e0 = tvv == tsl[4 * ti + 0];
                int e1 = tvv == tsl[4 * ti + 1];
                int e2 = tvv == tsl[4 * ti + 2];
                int e3 = tvv == tsl[4 * ti + 3];
                if (__ballot(e0 | e1 | e2 | e3)) {  // wave-uniform: tile has same-class pairs
                    hp[4 * ti + 0] = fmaxf(hp[4 * ti + 0], e0 ? v[0] : -INFINITY);
                    hp[4 * ti + 1] = fmaxf(hp[4 * ti + 1], e1 ? v[1] : -INFINITY);
                    hp[4 * ti + 2] = fmaxf(hp[4 * ti + 2], e2 ? v[2] : -INFINITY);
                    hp[4 * ti + 3] = fmaxf(hp[4 * ti + 3], e3 ? v[3] : -INFINITY);
                    mn[4 * ti + 0] = fminf(mn[4 * ti + 0], e0 ? INFINITY : v[0]);
                    mn[4 * ti + 1] = fminf(mn[4 * ti + 1], e1 ? INFINITY : v[1]);
                    mn[4 * ti + 2] = fminf(mn[4 * ti + 2], e2 ? INFINITY : v[2]);
                    mn[4 * ti + 3] = fminf(mn[4 * ti + 3], e3 ? INFINITY : v[3]);
                } else {  // fast path: all-negative tile
                    mn[4 * ti + 0] = fminf(mn[4 * ti + 0], v[0]);
                    mn[4 * ti + 1] = fminf(mn[4 * ti + 1], v[1]);
                    mn[4 * ti + 2] = fminf(mn[4 * ti + 2], v[2]);
                    mn[4 * ti + 3] = fminf(mn[4 * ti + 3], v[3]);
                }
            }
        }
    }

    // reduce across the 16 col-lanes; lane n==0 of each quad commits rows 4q+r
#pragma unroll
    for (int m = 1; m <= 8; m <<= 1) {
#pragma unroll
        for (int s = 0; s < 16; ++s) {
            hp[s] = fmaxf(hp[s], __shfl_xor(hp[s], m));
            mn[s] = fminf(mn[s], __shfl_xor(mn[s], m));
        }
    }
    if (n == 0) {
#pragma unroll
        for (int ti = 0; ti < 4; ++ti) {
#pragma unroll
            for (int r = 0; r < 4; ++r) {
                int i = rbase + 16 * ti + 4 * q + r;
                atomicMax(&wsHp[i], enc(hp[4 * ti + r]));
                atomicMin(&wsMn[i], enc(mn[4 * ti + r]));
            }
        }
    }
}

// Kernel C: single block, no atomics, writes out directly (no memset needed)
__global__ void finish_kernel(const float* __restrict__ P,
                              const unsigned* __restrict__ wsHp,
                              const unsigned* __restrict__ wsMn,
                              float* __restrict__ out) {
    int t = threadIdx.x;  // 1024 threads
    float sum = 0.0f;
#pragma unroll
    for (int k = 0; k < 8; ++k) {
        int i = t + 1024 * k;
        float Pi = P[i];
        float hp = sqrtf(fmaxf(Pi + dec(wsHp[i]), 0.0f));
        float hn = sqrtf(fmaxf(Pi + dec(wsMn[i]), 0.0f));
        sum += fmaxf(hp - hn + MARGIN, 0.0f);
    }
#pragma unroll
    for (int m = 32; m >= 1; m >>= 1) sum += __shfl_xor(sum, m);
    __shared__ float ws[16];
    if ((t & 63) == 0) ws[t >> 6] = sum;
    __syncthreads();
    if (t == 0) {
        float tot = 0.0f;
#pragma unroll
        for (int i = 0; i < 16; ++i) tot += ws[i];
        out[0] = tot * (1.0f / (float)N);
    }
}

extern "C" void kernel_launch(void* const* d_in, const int* in_sizes, int n_in,
                              void* d_out, int out_size, void* d_ws, size_t ws_size,
                              hipStream_t stream) {
    const float* x = (const float*)d_in[0];
    const int* tgt = (const int*)d_in[1];
    float* out = (float*)d_out;

    char* ws = (char*)d_ws;
    const size_t xb = (size_t)N * Dk * 2;  // 2 MB per bf16 copy
    unsigned short* XbA = (unsigned short*)ws;
    unsigned short* XbB = (unsigned short*)(ws + xb);
    uint2* QT = (uint2*)(ws + 2 * xb);
    float* P = (float*)(ws + 2 * xb + (size_t)N * 8);
    unsigned* wsHp = (unsigned*)(ws + 2 * xb + (size_t)N * 12);
    unsigned* wsMn = (unsigned*)(ws + 2 * xb + (size_t)N * 16);

    prep_kernel<<<N / 4, 256, 0, stream>>>(x, tgt, XbA, XbB, QT, P, wsHp, wsMn);
    main_kernel<<<512, 256, 0, stream>>>(XbA, XbB, QT, tgt, wsHp, wsMn);
    finish_kernel<<<1, 1024, 0, stream>>>(P, wsHp, wsMn, out);
}